// Round 4
// baseline (1728.307 us; speedup 1.0000x reference)
//
#include <hip/hip_runtime.h>

typedef unsigned short u16;
typedef __attribute__((ext_vector_type(8))) short bf16x8;
typedef __attribute__((ext_vector_type(4))) float f32x4;

#define MFMA16(A,B,C) __builtin_amdgcn_mfma_f32_16x16x32_bf16(A,B,C,0,0,0)

__device__ __forceinline__ u16 f2bf(float f){
    unsigned int u = __float_as_uint(f);
    u += 0x7fffu + ((u >> 16) & 1u);
    return (u16)(u >> 16);
}
__device__ __forceinline__ unsigned int pk2(float lo, float hi){
    return (unsigned int)f2bf(lo) | ((unsigned int)f2bf(hi) << 16);
}
__device__ __forceinline__ float upk(unsigned int u, int hi){
    return __uint_as_float(hi ? (u & 0xffff0000u) : (u << 16));
}
__device__ __forceinline__ float bf2f(u16 v){
    return __uint_as_float(((unsigned int)v) << 16);
}
__device__ __forceinline__ float fast_tanh(float p){
    float e2 = __expf(2.f * p);
    return 1.f - __fdividef(2.f, e2 + 1.f);
}
__device__ __forceinline__ void gload16(const u16* g, u16* l){
    __builtin_amdgcn_global_load_lds((const __attribute__((address_space(1))) void*)g,
                                     (__attribute__((address_space(3))) void*)l, 16, 0, 0);
}
// AGPR pin helpers: keep read-only per-row state out of the arch-VGPR class
__device__ __forceinline__ void aw(unsigned int &d, unsigned int v){
    asm volatile("v_accvgpr_write_b32 %0, %1" : "=a"(d) : "v"(v));
}
__device__ __forceinline__ unsigned int ar(const unsigned int &s){
    unsigned int r;
    asm volatile("v_accvgpr_read_b32 %0, %1" : "=v"(r) : "a"(s));
    return r;
}

// ---------------- weight pre-pack kernel ----------------
// ws layout (u16 each 65536): [0]=W1, [1]=W2, [2]=unused, [3]=W2T, [4]=Wc
// Style A (K=128,N=512; 0,3,4): q = nc(3b)|ks(2b)|t(2b)|l(6b)|j(3b)
// Style B (K=512,N=128; 1):     q = nc(3b)|ksl(1b)|nt(3b)|l(6b)|j(3b)
__global__ __launch_bounds__(256) void pack_weights_kernel(
    const float* __restrict__ W1, const float* __restrict__ W2,
    const float* __restrict__ Wc, u16* __restrict__ wp)
{
    int p = blockIdx.x * 256 + threadIdx.x;
    int which = p >> 16;
    int q = p & 65535;
    int j = q & 7, l = (q >> 3) & 63;
    int l15 = l & 15, l4 = l >> 4;
    float v;
    if (which == 0 || which == 3 || which == 4) {
        int t = (q >> 9) & 3, ks = (q >> 11) & 3, nc = q >> 13;
        int k = 32 * ks + l4 * 8 + j;
        int n = 64 * nc + 16 * t + l15;
        v = (which == 0) ? W1[k * 512 + n] : (which == 3) ? W2[n * 128 + k] : Wc[k * 512 + n];
    } else {
        int nt = (q >> 9) & 7, ksl = (q >> 12) & 1, nc = q >> 13;
        int k = 64 * nc + 32 * ksl + l4 * 8 + j;
        int n = 16 * nt + l15;
        v = (which == 1) ? W2[k * 128 + n] : W1[n * 512 + k];
    }
    wp[p] = f2bf(v);
}

// ---------------- fused CNF RK4 kernel ----------------
__global__ __launch_bounds__(256, 2) void cnf_mfma3_kernel(
    const float* __restrict__ x, const float* __restrict__ logpx,
    const float* __restrict__ cond, const float* __restrict__ e,
    const float* __restrict__ b1, const u16* __restrict__ wp,
    const float* __restrict__ bt, const float* __restrict__ b2,
    float* __restrict__ y_out, float* __restrict__ lp_out)
{
    __shared__ u16 s_w[2][2 * 8192];   // 64 KB double-buffered weight chunks
    __shared__ u16 s_t[4][16 * 72];    // 9 KB per-wave transpose buffers
    __shared__ u16 s_bt[512];
    __shared__ float s_b2[128];

    const int tid = threadIdx.x, wave = tid >> 6, lane = tid & 63;
    const int l15 = lane & 15, l4 = lane >> 4;
    const int rbase = blockIdx.x * 64 + wave * 16;

    const u16* W1p  = wp;
    const u16* W2p  = wp + 65536;
    const u16* W2Tp = wp + 196608;
    const u16* Wcp  = wp + 262144;
    u16* tw = &s_t[wave][0];

    auto stage_c = [&](int buf, int nc){      // Wc[nc] -> slot0 (16 KB)
        #pragma unroll
        for (int q = 0; q < 4; ++q){
            const int idx = wave * 4 + q;
            gload16(Wcp + nc * 8192 + idx * 512 + lane * 8, &s_w[buf][idx * 512]);
        }
    };
    auto stage_q = [&](int buf, int nc){      // W1[nc] -> slot0, W2T[nc] -> slot1
        #pragma unroll
        for (int q = 0; q < 8; ++q){
            const int idx = wave * 8 + q;
            const u16* src = (idx < 16) ? (W1p  + nc * 8192 + idx * 512)
                                        : (W2Tp + nc * 8192 + (idx - 16) * 512);
            gload16(src + lane * 8, &s_w[buf][idx * 512]);
        }
    };
    auto stage_main = [&](int buf, int nc){   // W1[nc] -> slot0, W2[nc] -> slot1
        #pragma unroll
        for (int q = 0; q < 8; ++q){
            const int idx = wave * 8 + q;
            const u16* src = (idx < 16) ? (W1p + nc * 8192 + idx * 512)
                                        : (W2p + nc * 8192 + (idx - 16) * 512);
            gload16(src + lane * 8, &s_w[buf][idx * 512]);
        }
    };

    stage_c(0, 0);                       // first prefetch ASAP
    s_bt[tid]       = f2bf(bt[tid]);
    s_bt[tid + 256] = f2bf(bt[tid + 256]);
    if (tid < 128) s_b2[tid] = b2[tid];

    unsigned int base_pk[8][4][2], q_pk[8][4][2];   // AGPR-pinned

    // ---- pass 1: base = cond@Wc + b1 (only cA live) ----
    {
        bf16x8 cA[4];
        #pragma unroll
        for (int p = 0; p < 2; ++p){
            #pragma unroll
            for (int i = 0; i < 16; ++i)
                tw[i * 72 + lane] = f2bf(cond[(size_t)(rbase + i) * 128 + p * 64 + lane]);
            #pragma unroll
            for (int ksl = 0; ksl < 2; ++ksl)
                cA[p * 2 + ksl] = *(const bf16x8*)&tw[l15 * 72 + ksl * 32 + l4 * 8];
        }
        #pragma unroll
        for (int nc = 0; nc < 8; ++nc){
            const int buf = nc & 1;
            __syncthreads();
            if (nc < 7) stage_c(buf ^ 1, nc + 1);
            else        stage_q(buf ^ 1, 0);
            #pragma unroll
            for (int tt = 0; tt < 4; ++tt){
                f32x4 ab = {0.f, 0.f, 0.f, 0.f};
                #pragma unroll
                for (int ks = 0; ks < 4; ++ks)
                    ab = MFMA16(cA[ks], *(const bf16x8*)&s_w[buf][(ks * 4 + tt) * 512 + lane * 8], ab);
                const float b1v = b1[nc * 64 + tt * 16 + l15];
                #pragma unroll
                for (int rr = 0; rr < 2; ++rr)
                    aw(base_pk[nc][tt][rr], pk2(ab[2 * rr] + b1v, ab[2 * rr + 1] + b1v));
            }
        }
    }

    // ---- pass 2: q = (e@W1) ⊙ (e@W2T) (only eA live) ----
    {
        bf16x8 eA[4];
        #pragma unroll
        for (int p = 0; p < 2; ++p){
            #pragma unroll
            for (int i = 0; i < 16; ++i)
                tw[i * 72 + lane] = f2bf(e[(size_t)(rbase + i) * 128 + p * 64 + lane]);
            #pragma unroll
            for (int ksl = 0; ksl < 2; ++ksl)
                eA[p * 2 + ksl] = *(const bf16x8*)&tw[l15 * 72 + ksl * 32 + l4 * 8];
        }
        #pragma unroll
        for (int nc = 0; nc < 8; ++nc){
            const int buf = nc & 1;
            __syncthreads();
            if (nc < 7) stage_q(buf ^ 1, nc + 1);
            else        stage_main(buf ^ 1, 0);
            #pragma unroll
            for (int tt = 0; tt < 4; ++tt){
                f32x4 ew = {0.f, 0.f, 0.f, 0.f};
                #pragma unroll
                for (int ks = 0; ks < 4; ++ks)
                    ew = MFMA16(eA[ks], *(const bf16x8*)&s_w[buf][(ks * 4 + tt) * 512 + lane * 8], ew);
                f32x4 e2 = {0.f, 0.f, 0.f, 0.f};
                #pragma unroll
                for (int ks = 0; ks < 4; ++ks)
                    e2 = MFMA16(eA[ks], *(const bf16x8*)&s_w[buf][8192 + (ks * 4 + tt) * 512 + lane * 8], e2);
                #pragma unroll
                for (int rr = 0; rr < 2; ++rr)
                    aw(q_pk[nc][tt][rr], pk2(ew[2 * rr] * e2[2 * rr], ew[2 * rr + 1] * e2[2 * rr + 1]));
            }
        }
    }

    // ---- load x0 (packed bf16), build xxA fragments ----
    unsigned int xs_pk[8][2];
    bf16x8 xxA[4];
    #pragma unroll
    for (int p = 0; p < 2; ++p){
        #pragma unroll
        for (int tt = 0; tt < 4; ++tt){
            const int nt = p * 4 + tt;
            #pragma unroll
            for (int rr = 0; rr < 2; ++rr){
                const float a0 = x[(size_t)(rbase + l4 * 4 + 2 * rr)     * 128 + nt * 16 + l15];
                const float a1 = x[(size_t)(rbase + l4 * 4 + 2 * rr + 1) * 128 + nt * 16 + l15];
                xs_pk[nt][rr] = pk2(a0, a1);
                tw[(l4 * 4 + 2 * rr)     * 72 + tt * 16 + l15] = (u16)(xs_pk[nt][rr] & 0xffffu);
                tw[(l4 * 4 + 2 * rr + 1) * 72 + tt * 16 + l15] = (u16)(xs_pk[nt][rr] >> 16);
            }
        }
        #pragma unroll
        for (int ksl = 0; ksl < 2; ++ksl)
            xxA[p * 2 + ksl] = *(const bf16x8*)&tw[l15 * 72 + ksl * 32 + l4 * 8];
    }

    // ---- main RK4 loop ----
    f32x4 acc[8];
    unsigned int dxc_pk[8][2];
    float divacc[4] = {0.f, 0.f, 0.f, 0.f};
    #pragma unroll
    for (int nt = 0; nt < 8; ++nt){
        acc[nt] = {0.f, 0.f, 0.f, 0.f};
        dxc_pk[nt][0] = 0u; dxc_pk[nt][1] = 0u;
    }

    #pragma unroll 1
    for (int st = 0; st < 16; ++st){
        const int stg = st & 3;
        const float tcur = 0.25f * (float)(st >> 2) + ((stg == 0) ? 0.f : (stg == 3) ? 0.25f : 0.125f);
        const float wcur = (stg == 1 || stg == 2) ? 2.f : 1.f;

        #pragma unroll
        for (int nc = 0; nc < 8; ++nc){
            const int buf = nc & 1;
            __syncthreads();
            if (!(st == 15 && nc == 7)) stage_main(buf ^ 1, (nc + 1) & 7);

            // GEMM1 per 16-col tile: pre = xx@W1 + base + t*bt; then tanh/div/h
            #pragma unroll
            for (int tt = 0; tt < 4; ++tt){
                const float btv = bf2f(s_bt[nc * 64 + tt * 16 + l15]);
                const unsigned int b0 = ar(base_pk[nc][tt][0]);
                const unsigned int bž = ar(base_pk[nc][tt][1]);
                f32x4 pre;
                pre[0] = upk(b0, 0) + tcur * btv;
                pre[1] = upk(b0, 1) + tcur * btv;
                pre[2] = upk(bž, 0) + tcur * btv;
                pre[3] = upk(bž, 1) + tcur * btv;
                #pragma unroll
                for (int ks = 0; ks < 4; ++ks)
                    pre = MFMA16(xxA[ks], *(const bf16x8*)&s_w[buf][(ks * 4 + tt) * 512 + lane * 8], pre);
                const unsigned int q0 = ar(q_pk[nc][tt][0]);
                const unsigned int q1 = ar(q_pk[nc][tt][1]);
                #pragma unroll
                for (int r = 0; r < 4; ++r){
                    const float h = fast_tanh(pre[r]);
                    const float qv = upk((r < 2) ? q0 : q1, r & 1);
                    divacc[r] += wcur * ((1.f - h * h) * qv);
                    tw[(l4 * 4 + r) * 72 + tt * 16 + l15] = f2bf(h);
                }
            }

            // GEMM2: dx += h@W2  (K-slice 64)
            #pragma unroll
            for (int ksl = 0; ksl < 2; ++ksl){
                const bf16x8 hA = *(const bf16x8*)&tw[l15 * 72 + ksl * 32 + l4 * 8];
                #pragma unroll
                for (int nt = 0; nt < 8; ++nt)
                    acc[nt] = MFMA16(hA, *(const bf16x8*)&s_w[buf][8192 + (ksl * 8 + nt) * 512 + lane * 8], acc[nt]);
            }
        }

        // ---- stage epilogue fused with next-xx transpose ----
        const float adt = (stg == 2) ? 0.25f : 0.125f;
        #pragma unroll
        for (int p = 0; p < 2; ++p){
            #pragma unroll
            for (int tt = 0; tt < 4; ++tt){
                const int nt = p * 4 + tt;
                const float b2v = s_b2[nt * 16 + l15];
                #pragma unroll
                for (int rr = 0; rr < 2; ++rr){
                    const float d0 = acc[nt][2 * rr]     + b2v;
                    const float d1 = acc[nt][2 * rr + 1] + b2v;
                    const float c0 = upk(dxc_pk[nt][rr], 0) + wcur * d0;
                    const float c1 = upk(dxc_pk[nt][rr], 1) + wcur * d1;
                    const float x00 = upk(xs_pk[nt][rr], 0);
                    const float x01 = upk(xs_pk[nt][rr], 1);
                    float xn0, xn1;
                    if (stg < 3){
                        dxc_pk[nt][rr] = pk2(c0, c1);
                        xn0 = x00 + adt * d0;
                        xn1 = x01 + adt * d1;
                    } else {
                        dxc_pk[nt][rr] = 0u;
                        xn0 = x00 + (0.25f / 6.f) * c0;
                        xn1 = x01 + (0.25f / 6.f) * c1;
                        xs_pk[nt][rr] = pk2(xn0, xn1);
                    }
                    if (st < 15){
                        tw[(l4 * 4 + 2 * rr)     * 72 + tt * 16 + l15] = f2bf(xn0);
                        tw[(l4 * 4 + 2 * rr + 1) * 72 + tt * 16 + l15] = f2bf(xn1);
                    }
                    acc[nt][2 * rr] = 0.f; acc[nt][2 * rr + 1] = 0.f;
                }
            }
            if (st < 15){
                #pragma unroll
                for (int ksl = 0; ksl < 2; ++ksl)
                    xxA[p * 2 + ksl] = *(const bf16x8*)&tw[l15 * 72 + ksl * 32 + l4 * 8];
            }
        }
    }

    // ---- outputs ----
    #pragma unroll
    for (int nt = 0; nt < 8; ++nt)
        #pragma unroll
        for (int rr = 0; rr < 2; ++rr){
            y_out[(size_t)(rbase + l4 * 4 + 2 * rr)     * 128 + nt * 16 + l15] = upk(xs_pk[nt][rr], 0);
            y_out[(size_t)(rbase + l4 * 4 + 2 * rr + 1) * 128 + nt * 16 + l15] = upk(xs_pk[nt][rr], 1);
        }

    #pragma unroll
    for (int r = 0; r < 4; ++r){
        float d = divacc[r];
        d += __shfl_xor(d, 1);
        d += __shfl_xor(d, 2);
        d += __shfl_xor(d, 4);
        d += __shfl_xor(d, 8);
        if (l15 == 0){
            const int row = rbase + l4 * 4 + r;
            lp_out[row] = logpx[row] - (0.25f / 6.f) * d;
        }
    }
}

extern "C" void kernel_launch(void* const* d_in, const int* in_sizes, int n_in,
                              void* d_out, int out_size, void* d_ws, size_t ws_size,
                              hipStream_t stream) {
    const float* x     = (const float*)d_in[0];
    const float* logpx = (const float*)d_in[1];
    const float* cond  = (const float*)d_in[2];
    const float* e     = (const float*)d_in[3];
    const float* W1    = (const float*)d_in[4];
    const float* Wc    = (const float*)d_in[5];
    const float* bt    = (const float*)d_in[6];
    const float* b1    = (const float*)d_in[7];
    const float* W2    = (const float*)d_in[8];
    const float* b2    = (const float*)d_in[9];

    u16* wp = (u16*)d_ws;                       // 5*65536 u16 = 640 KB
    float* y_out  = (float*)d_out;
    float* lp_out = y_out + (size_t)32768 * 128;

    hipLaunchKernelGGL(pack_weights_kernel, dim3(1280), dim3(256), 0, stream, W1, W2, Wc, wp);
    hipLaunchKernelGGL(cnf_mfma3_kernel, dim3(512), dim3(256), 0, stream,
                       x, logpx, cond, e, b1, wp, bt, b2, y_out, lp_out);
}

// Round 5
// 1143.970 us; speedup vs baseline: 1.5108x; 1.5108x over previous
//
#include <hip/hip_runtime.h>

typedef unsigned short u16;
typedef __attribute__((ext_vector_type(8))) short bf16x8;
typedef __attribute__((ext_vector_type(4))) float f32x4;

#define MFMA16(A,B,C) __builtin_amdgcn_mfma_f32_16x16x32_bf16(A,B,C,0,0,0)

__device__ __forceinline__ u16 f2bf(float f){
    unsigned int u = __float_as_uint(f);
    u += 0x7fffu + ((u >> 16) & 1u);
    return (u16)(u >> 16);
}
__device__ __forceinline__ unsigned int pk2(float lo, float hi){
    return (unsigned int)f2bf(lo) | ((unsigned int)f2bf(hi) << 16);
}
__device__ __forceinline__ float upk(unsigned int u, int hi){
    return __uint_as_float(hi ? (u & 0xffff0000u) : (u << 16));
}
__device__ __forceinline__ float bf2f(u16 v){
    return __uint_as_float(((unsigned int)v) << 16);
}
__device__ __forceinline__ float fast_tanh(float p){
    float e2 = __expf(2.f * p);
    return 1.f - __fdividef(2.f, e2 + 1.f);
}
__device__ __forceinline__ void gload16(const u16* g, u16* l){
    __builtin_amdgcn_global_load_lds((const __attribute__((address_space(1))) void*)g,
                                     (__attribute__((address_space(3))) void*)l, 16, 0, 0);
}

// ---------------- weight pre-pack kernel (unchanged, validated) ----------------
// ws layout (u16 each 65536): [0]=W1, [1]=W2, [2]=W1T(unused), [3]=W2T, [4]=Wc
__global__ __launch_bounds__(256) void pack_weights_kernel(
    const float* __restrict__ W1, const float* __restrict__ W2,
    const float* __restrict__ Wc, u16* __restrict__ wp)
{
    int p = blockIdx.x * 256 + threadIdx.x;
    int which = p >> 16;
    int q = p & 65535;
    int j = q & 7, l = (q >> 3) & 63;
    int l15 = l & 15, l4 = l >> 4;
    float v;
    if (which == 0 || which == 3 || which == 4) {
        int t = (q >> 9) & 3, ks = (q >> 11) & 3, nc = q >> 13;
        int k = 32 * ks + l4 * 8 + j;
        int n = 64 * nc + 16 * t + l15;
        v = (which == 0) ? W1[k * 512 + n] : (which == 3) ? W2[n * 128 + k] : Wc[k * 512 + n];
    } else {
        int nt = (q >> 9) & 7, ksl = (q >> 12) & 1, nc = q >> 13;
        int k = 64 * nc + 32 * ksl + l4 * 8 + j;
        int n = 16 * nt + l15;
        v = (which == 1) ? W2[k * 128 + n] : W1[n * 512 + k];
    }
    wp[p] = f2bf(v);
}

// ---------------- fused CNF RK4 kernel: wave-pair split, no spill ----------------
__global__ __launch_bounds__(256, 2) void cnf_mfma4_kernel(
    const float* __restrict__ x, const float* __restrict__ logpx,
    const float* __restrict__ cond, const float* __restrict__ e,
    const float* __restrict__ b1, const u16* __restrict__ wp,
    const float* __restrict__ bt, const float* __restrict__ b2,
    float* __restrict__ y_out, float* __restrict__ lp_out)
{
    __shared__ __align__(16) u16 s_w[2][2 * 8192];      // 64 KB dbuf weight chunks
    __shared__ __align__(16) u16 s_h[2][2][16 * 72];    // 9 KB per-pair exchange buffers
    __shared__ u16 s_bt[512];
    __shared__ float s_b2[128];
    __shared__ float s_red[2][2][16];

    const int tid = threadIdx.x, wave = tid >> 6, lane = tid & 63;
    const int l15 = lane & 15, l4 = lane >> 4;
    const int pair = wave >> 1, half = wave & 1;
    const int rbase = blockIdx.x * 32 + pair * 16;

    const u16* W1p  = wp;
    const u16* W2p  = wp + 65536;
    const u16* W2Tp = wp + 196608;
    const u16* Wcp  = wp + 262144;

    u16 (*hb)[16 * 72] = s_h[pair];

    auto stage_c = [&](int buf, int nc){      // Wc[nc] -> slot0
        #pragma unroll
        for (int q = 0; q < 4; ++q){
            const int idx = wave * 4 + q;
            gload16(Wcp + nc * 8192 + idx * 512 + lane * 8, &s_w[buf][idx * 512]);
        }
    };
    auto stage_q = [&](int buf, int nc){      // W1[nc] -> slot0, W2T[nc] -> slot1
        #pragma unroll
        for (int q = 0; q < 8; ++q){
            const int idx = wave * 8 + q;
            const u16* src = (idx < 16) ? (W1p  + nc * 8192 + idx * 512)
                                        : (W2Tp + nc * 8192 + (idx - 16) * 512);
            gload16(src + lane * 8, &s_w[buf][idx * 512]);
        }
    };
    auto stage_main = [&](int buf, int nc){   // W1[nc] -> slot0, W2[nc] -> slot1
        #pragma unroll
        for (int q = 0; q < 8; ++q){
            const int idx = wave * 8 + q;
            const u16* src = (idx < 16) ? (W1p + nc * 8192 + idx * 512)
                                        : (W2p + nc * 8192 + (idx - 16) * 512);
            gload16(src + lane * 8, &s_w[buf][idx * 512]);
        }
    };
    auto readA = [&](int b2i, int ks2)->bf16x8 {
        return *(const bf16x8*)&hb[b2i][l15 * 72 + ks2 * 32 + l4 * 8];
    };
    auto fill128 = [&](const float* src){     // pair fills 16x128 transpose area
        #pragma unroll
        for (int i = 0; i < 8; ++i){
            const int row = half * 8 + i;
            hb[0][row * 72 + lane] = f2bf(src[(size_t)(rbase + row) * 128 + lane]);
            hb[1][row * 72 + lane] = f2bf(src[(size_t)(rbase + row) * 128 + 64 + lane]);
        }
    };

    stage_c(0, 0);                            // first prefetch ASAP
    s_bt[tid]       = f2bf(bt[tid]);
    s_bt[tid + 256] = f2bf(bt[tid + 256]);
    if (tid < 128) s_b2[tid] = b2[tid];

    unsigned int base_pk[8][2][2], q_pk[8][2][2];

    // ---- pass 1: base = cond@Wc + b1 (wave's 2 tt per chunk) ----
    {
        bf16x8 cA[4];
        fill128(cond);
        #pragma unroll
        for (int nc = 0; nc < 8; ++nc){
            const int buf = nc & 1;
            __syncthreads();
            if (nc == 0){
                #pragma unroll
                for (int ks = 0; ks < 4; ++ks) cA[ks] = readA(ks >> 1, ks & 1);
            }
            if (nc < 7) stage_c(buf ^ 1, nc + 1);
            else        stage_q(buf ^ 1, 0);
            #pragma unroll
            for (int ttl = 0; ttl < 2; ++ttl){
                const int tt = half * 2 + ttl;
                f32x4 ab = {0.f, 0.f, 0.f, 0.f};
                #pragma unroll
                for (int ks = 0; ks < 4; ++ks)
                    ab = MFMA16(cA[ks], *(const bf16x8*)&s_w[buf][(ks * 4 + tt) * 512 + lane * 8], ab);
                const float b1v = b1[nc * 64 + tt * 16 + l15];
                #pragma unroll
                for (int rr = 0; rr < 2; ++rr)
                    base_pk[nc][ttl][rr] = pk2(ab[2 * rr] + b1v, ab[2 * rr + 1] + b1v);
            }
        }
    }

    // ---- pass 2: q = (e@W1) ⊙ (e@W2T) (wave's 2 tt per chunk) ----
    {
        bf16x8 eA[4];
        fill128(e);
        #pragma unroll
        for (int nc = 0; nc < 8; ++nc){
            const int buf = nc & 1;
            __syncthreads();
            if (nc == 0){
                #pragma unroll
                for (int ks = 0; ks < 4; ++ks) eA[ks] = readA(ks >> 1, ks & 1);
            }
            if (nc < 7) stage_q(buf ^ 1, nc + 1);
            else        stage_main(buf ^ 1, 0);
            #pragma unroll
            for (int ttl = 0; ttl < 2; ++ttl){
                const int tt = half * 2 + ttl;
                f32x4 ew = {0.f, 0.f, 0.f, 0.f}, e2 = {0.f, 0.f, 0.f, 0.f};
                #pragma unroll
                for (int ks = 0; ks < 4; ++ks){
                    ew = MFMA16(eA[ks], *(const bf16x8*)&s_w[buf][(ks * 4 + tt) * 512 + lane * 8], ew);
                    e2 = MFMA16(eA[ks], *(const bf16x8*)&s_w[buf][8192 + (ks * 4 + tt) * 512 + lane * 8], e2);
                }
                #pragma unroll
                for (int rr = 0; rr < 2; ++rr)
                    q_pk[nc][ttl][rr] = pk2(ew[2 * rr] * e2[2 * rr], ew[2 * rr + 1] * e2[2 * rr + 1]);
            }
        }
    }

    // ---- x0: wave's 4 nt (D-half), packed bf16; write to pair xx area ----
    unsigned int xs_pk[4][2];
    #pragma unroll
    for (int ntl = 0; ntl < 4; ++ntl)
        #pragma unroll
        for (int rr = 0; rr < 2; ++rr){
            const float a0 = x[(size_t)(rbase + l4 * 4 + 2 * rr)     * 128 + half * 64 + ntl * 16 + l15];
            const float a1 = x[(size_t)(rbase + l4 * 4 + 2 * rr + 1) * 128 + half * 64 + ntl * 16 + l15];
            xs_pk[ntl][rr] = pk2(a0, a1);
            hb[half][(l4 * 4 + 2 * rr)     * 72 + ntl * 16 + l15] = (u16)(xs_pk[ntl][rr] & 0xffffu);
            hb[half][(l4 * 4 + 2 * rr + 1) * 72 + ntl * 16 + l15] = (u16)(xs_pk[ntl][rr] >> 16);
        }

    // ---- main RK4 loop ----
    f32x4 acc[4];
    unsigned int dxc_pk[4][2];
    float divacc[4] = {0.f, 0.f, 0.f, 0.f};
    #pragma unroll
    for (int ntl = 0; ntl < 4; ++ntl){
        acc[ntl] = {0.f, 0.f, 0.f, 0.f};
        dxc_pk[ntl][0] = 0u; dxc_pk[ntl][1] = 0u;
    }
    bf16x8 xxA[4];

    #pragma unroll 1
    for (int st = 0; st < 16; ++st){
        const int stg = st & 3;
        const float tcur = 0.25f * (float)(st >> 2) + ((stg == 0) ? 0.f : (stg == 3) ? 0.25f : 0.125f);
        const float wcur = (stg == 1 || stg == 2) ? 2.f : 1.f;

        __syncthreads();                       // B0: xn visible (and stage-0 weights drained)
        #pragma unroll
        for (int ks = 0; ks < 4; ++ks) xxA[ks] = readA(ks >> 1, ks & 1);
        __syncthreads();                       // B1: xxA reads drained -> hb free

        #pragma unroll
        for (int nc = 0; nc < 8; ++nc){
            const int buf = nc & 1;
            if (nc > 0) __syncthreads();       // B_top: weights[nc] ready, prev hA reads drained
            if (!(st == 15 && nc == 7)) stage_main(buf ^ 1, (nc + 1) & 7);

            // GEMM1 (my 2 tt): pre = xx@W1 + base + t*bt; h -> pair buffer
            #pragma unroll
            for (int ttl = 0; ttl < 2; ++ttl){
                const int tt = half * 2 + ttl;
                const float btv = bf2f(s_bt[nc * 64 + tt * 16 + l15]);
                f32x4 pre;
                pre[0] = upk(base_pk[nc][ttl][0], 0) + tcur * btv;
                pre[1] = upk(base_pk[nc][ttl][0], 1) + tcur * btv;
                pre[2] = upk(base_pk[nc][ttl][1], 0) + tcur * btv;
                pre[3] = upk(base_pk[nc][ttl][1], 1) + tcur * btv;
                #pragma unroll
                for (int ks = 0; ks < 4; ++ks)
                    pre = MFMA16(xxA[ks], *(const bf16x8*)&s_w[buf][(ks * 4 + tt) * 512 + lane * 8], pre);
                #pragma unroll
                for (int r = 0; r < 4; ++r){
                    const float h = fast_tanh(pre[r]);
                    divacc[r] += wcur * (1.f - h * h) * upk(q_pk[nc][ttl][r >> 1], r & 1);
                    hb[0][(l4 * 4 + r) * 72 + tt * 16 + l15] = f2bf(h);
                }
            }
            __syncthreads();                   // B_mid: h exchanged across pair

            // GEMM2 (my 4 nt): dx += h@W2 over this chunk's K=64
            #pragma unroll
            for (int ksl = 0; ksl < 2; ++ksl){
                const bf16x8 hA = *(const bf16x8*)&hb[0][l15 * 72 + ksl * 32 + l4 * 8];
                #pragma unroll
                for (int ntl = 0; ntl < 4; ++ntl){
                    const int nt = half * 4 + ntl;
                    acc[ntl] = MFMA16(hA, *(const bf16x8*)&s_w[buf][8192 + (ksl * 8 + nt) * 512 + lane * 8], acc[ntl]);
                }
            }
        }
        __syncthreads();                       // B_A: all hA reads drained; hb free for xn

        // ---- stage epilogue: RK4 combine + write next xx (bf16) ----
        const float adt = (stg == 2) ? 0.25f : 0.125f;
        #pragma unroll
        for (int ntl = 0; ntl < 4; ++ntl){
            const float b2v = s_b2[half * 64 + ntl * 16 + l15];
            #pragma unroll
            for (int rr = 0; rr < 2; ++rr){
                const float d0 = acc[ntl][2 * rr]     + b2v;
                const float d1 = acc[ntl][2 * rr + 1] + b2v;
                const float c0 = upk(dxc_pk[ntl][rr], 0) + wcur * d0;
                const float c1 = upk(dxc_pk[ntl][rr], 1) + wcur * d1;
                const float x00 = upk(xs_pk[ntl][rr], 0);
                const float x01 = upk(xs_pk[ntl][rr], 1);
                float xn0, xn1;
                if (stg < 3){
                    dxc_pk[ntl][rr] = pk2(c0, c1);
                    xn0 = x00 + adt * d0;
                    xn1 = x01 + adt * d1;
                } else {
                    dxc_pk[ntl][rr] = 0u;
                    xn0 = x00 + (0.25f / 6.f) * c0;
                    xn1 = x01 + (0.25f / 6.f) * c1;
                    xs_pk[ntl][rr] = pk2(xn0, xn1);
                }
                if (st < 15){
                    hb[half][(l4 * 4 + 2 * rr)     * 72 + ntl * 16 + l15] = f2bf(xn0);
                    hb[half][(l4 * 4 + 2 * rr + 1) * 72 + ntl * 16 + l15] = f2bf(xn1);
                }
                acc[ntl][2 * rr] = 0.f; acc[ntl][2 * rr + 1] = 0.f;
            }
        }
    }

    // ---- outputs ----
    #pragma unroll
    for (int ntl = 0; ntl < 4; ++ntl)
        #pragma unroll
        for (int rr = 0; rr < 2; ++rr){
            y_out[(size_t)(rbase + l4 * 4 + 2 * rr)     * 128 + half * 64 + ntl * 16 + l15] = upk(xs_pk[ntl][rr], 0);
            y_out[(size_t)(rbase + l4 * 4 + 2 * rr + 1) * 128 + half * 64 + ntl * 16 + l15] = upk(xs_pk[ntl][rr], 1);
        }

    // ---- logpy: reduce within wave (l15 groups), then across pair via LDS ----
    #pragma unroll
    for (int r = 0; r < 4; ++r){
        float d = divacc[r];
        d += __shfl_xor(d, 1);
        d += __shfl_xor(d, 2);
        d += __shfl_xor(d, 4);
        d += __shfl_xor(d, 8);
        if (l15 == 0) s_red[pair][half][l4 * 4 + r] = d;
    }
    __syncthreads();
    if (half == 0 && l15 == 0){
        #pragma unroll
        for (int r = 0; r < 4; ++r){
            const int row16 = l4 * 4 + r;
            const int row = rbase + row16;
            lp_out[row] = logpx[row] - (0.25f / 6.f) * (s_red[pair][0][row16] + s_red[pair][1][row16]);
        }
    }
}

extern "C" void kernel_launch(void* const* d_in, const int* in_sizes, int n_in,
                              void* d_out, int out_size, void* d_ws, size_t ws_size,
                              hipStream_t stream) {
    const float* x     = (const float*)d_in[0];
    const float* logpx = (const float*)d_in[1];
    const float* cond  = (const float*)d_in[2];
    const float* e     = (const float*)d_in[3];
    const float* W1    = (const float*)d_in[4];
    const float* Wc    = (const float*)d_in[5];
    const float* bt    = (const float*)d_in[6];
    const float* b1    = (const float*)d_in[7];
    const float* W2    = (const float*)d_in[8];
    const float* b2    = (const float*)d_in[9];

    u16* wp = (u16*)d_ws;                       // 5*65536 u16 = 640 KB
    float* y_out  = (float*)d_out;
    float* lp_out = y_out + (size_t)32768 * 128;

    hipLaunchKernelGGL(pack_weights_kernel, dim3(1280), dim3(256), 0, stream, W1, W2, Wc, wp);
    hipLaunchKernelGGL(cnf_mfma4_kernel, dim3(1024), dim3(256), 0, stream,
                       x, logpx, cond, e, b1, wp, bt, b2, y_out, lp_out);
}